// Round 3
// baseline (2576.696 us; speedup 1.0000x reference)
//
#include <hip/hip_runtime.h>

#define N_NODES 100000
#define N_EDGES 3200000
#define IN_DIM 128
#define HID 64

#define NPB 32                 // nodes per bucket
#define NBUCK (N_NODES / NPB)  // 3125, exact
#define NREG 8                 // stage regions (XCD proxy via blockIdx&7)
#define CAP 320                // slots per (region,bucket); mean 128, sd ~11 -> 17 sd margin

typedef __attribute__((ext_vector_type(8))) short short8;
typedef __attribute__((ext_vector_type(4))) float f32x4;

__device__ inline float bf2f(unsigned short u) {
    union { unsigned int u; float f; } c;
    c.u = ((unsigned int)u) << 16;
    return c.f;
}
__device__ inline unsigned short f2bf(float f) {
    union { float f; unsigned int u; } c;
    c.f = f;
    unsigned int u = c.u;
    return (unsigned short)((u + 0x7fffu + ((u >> 16) & 1u)) >> 16);  // RNE
}
// load 8 contiguous fp32, convert to bf16x8 MFMA fragment
__device__ inline short8 cvt8(const float* __restrict__ p) {
    f32x4 lo = *reinterpret_cast<const f32x4*>(p);
    f32x4 hi = *reinterpret_cast<const f32x4*>(p + 4);
    short8 r;
#pragma unroll
    for (int j = 0; j < 4; ++j) { r[j] = (short)f2bf(lo[j]); r[4 + j] = (short)f2bf(hi[j]); }
    return r;
}

// ---------------------------------------------------------------------------
// fc + relu: h0 = relu(x @ W^T + b), x:[N,128] fp32, W:[64,128] fp32, h0 bf16.
// One wave = 16-node x 64-feature tile, 16 MFMAs.
// A: x[m=lane&15][k=quad*8+j]; B: W[n=lane&15][k=quad*8+j]; D: col=lane&15, row=quad*4+reg.
// ---------------------------------------------------------------------------
__global__ __launch_bounds__(256) void fc_kernel(
    const float* __restrict__ x, const float* __restrict__ W,
    const float* __restrict__ b, unsigned short* __restrict__ h0) {
    int lane = threadIdx.x & 63;
    int wtile = (int)((blockIdx.x * blockDim.x + threadIdx.x) >> 6);
    if (wtile >= N_NODES / 16) return;
    int col = lane & 15, quad = lane >> 4;

    short8 bw[4][4];
#pragma unroll
    for (int nt = 0; nt < 4; ++nt)
#pragma unroll
        for (int ks = 0; ks < 4; ++ks)
            bw[nt][ks] = cvt8(W + (nt * 16 + col) * IN_DIM + ks * 32 + quad * 8);

    f32x4 acc[4];
#pragma unroll
    for (int nt = 0; nt < 4; ++nt) acc[nt] = {0.f, 0.f, 0.f, 0.f};

    int node0 = wtile * 16;
    const float* xrow = x + (size_t)(node0 + col) * IN_DIM + quad * 8;
#pragma unroll
    for (int ks = 0; ks < 4; ++ks) {
        short8 a = cvt8(xrow + ks * 32);
#pragma unroll
        for (int nt = 0; nt < 4; ++nt)
            acc[nt] = __builtin_amdgcn_mfma_f32_16x16x32_bf16(a, bw[nt][ks], acc[nt], 0, 0, 0);
    }

#pragma unroll
    for (int nt = 0; nt < 4; ++nt) {
        float bias = b[nt * 16 + col];
#pragma unroll
        for (int r = 0; r < 4; ++r) {
            float v = acc[nt][r] + bias;
            v = v > 0.f ? v : 0.f;
            h0[(size_t)(node0 + quad * 4 + r) * HID + nt * 16 + col] = f2bf(v);
        }
    }
}

// ---------------------------------------------------------------------------
// SAGE linear: hout = (agg @ Wl^T + bl) + (hin @ Wr^T) [+relu]. agg/hin/hout bf16.
// A-frags load directly from bf16; B-frags cvt from fp32 weights.
// ---------------------------------------------------------------------------
__global__ __launch_bounds__(256) void sage_kernel(
    const unsigned short* __restrict__ agg, const unsigned short* __restrict__ hin,
    const float* __restrict__ Wl, const float* __restrict__ bl,
    const float* __restrict__ Wr, unsigned short* __restrict__ hout, int do_relu) {
    int lane = threadIdx.x & 63;
    int wtile = (int)((blockIdx.x * blockDim.x + threadIdx.x) >> 6);
    if (wtile >= N_NODES / 16) return;
    int col = lane & 15, quad = lane >> 4;

    short8 bwl[4][2], bwr[4][2];
#pragma unroll
    for (int nt = 0; nt < 4; ++nt)
#pragma unroll
        for (int ks = 0; ks < 2; ++ks) {
            bwl[nt][ks] = cvt8(Wl + (nt * 16 + col) * HID + ks * 32 + quad * 8);
            bwr[nt][ks] = cvt8(Wr + (nt * 16 + col) * HID + ks * 32 + quad * 8);
        }

    f32x4 acc[4];
#pragma unroll
    for (int nt = 0; nt < 4; ++nt) acc[nt] = {0.f, 0.f, 0.f, 0.f};

    int node0 = wtile * 16;
    const unsigned short* arow = agg + (size_t)(node0 + col) * HID + quad * 8;
    const unsigned short* hrow = hin + (size_t)(node0 + col) * HID + quad * 8;
#pragma unroll
    for (int ks = 0; ks < 2; ++ks) {
        short8 aA = *reinterpret_cast<const short8*>(arow + ks * 32);
#pragma unroll
        for (int nt = 0; nt < 4; ++nt)
            acc[nt] = __builtin_amdgcn_mfma_f32_16x16x32_bf16(aA, bwl[nt][ks], acc[nt], 0, 0, 0);
        short8 aH = *reinterpret_cast<const short8*>(hrow + ks * 32);
#pragma unroll
        for (int nt = 0; nt < 4; ++nt)
            acc[nt] = __builtin_amdgcn_mfma_f32_16x16x32_bf16(aH, bwr[nt][ks], acc[nt], 0, 0, 0);
    }

#pragma unroll
    for (int nt = 0; nt < 4; ++nt) {
        float bias = bl[nt * 16 + col];
#pragma unroll
        for (int r = 0; r < 4; ++r) {
            float v = acc[nt][r] + bias;
            if (do_relu) v = v > 0.f ? v : 0.f;
            hout[(size_t)(node0 + quad * 4 + r) * HID + nt * 16 + col] = f2bf(v);
        }
    }
}

// ---------------------------------------------------------------------------
// Binning: edge -> packed (src<<5 | dst&31) appended to (region,bucket) slab.
// Region = blockIdx&7 (XCD locality proxy: keeps a cache line's writers on one
// XCD so appends merge in L2 -> writeback ~= payload, not 64B/edge).
// ---------------------------------------------------------------------------
__global__ __launch_bounds__(256) void bin_kernel(
    const int* __restrict__ ei, unsigned int* __restrict__ stage,
    int* __restrict__ cnt) {
    int e = blockIdx.x * blockDim.x + threadIdx.x;
    if (e >= N_EDGES) return;
    int dst = ei[N_EDGES + e];
    int src = ei[e];
    int b = dst >> 5;
    int r = blockIdx.x & (NREG - 1);
    int slot = r * NBUCK + b;
    int pos = atomicAdd(&cnt[slot], 1);
    if (pos < CAP) stage[(size_t)slot * CAP + pos] = ((unsigned int)src << 5) | (dst & 31);
}

// ---------------------------------------------------------------------------
// Bucketed mean aggregation: one block per bucket (32 nodes). LDS acc[32][64]
// fp32 via ds_add_f32 atomics; degree counted in LDS. h bf16 in, agg bf16 out.
// Each wave takes one staged edge: broadcast u32 + 128B coalesced row gather.
// ---------------------------------------------------------------------------
__global__ __launch_bounds__(256) void agg_kernel(
    const unsigned short* __restrict__ h, const unsigned int* __restrict__ stage,
    const int* __restrict__ cnt, unsigned short* __restrict__ out) {
    __shared__ float acc[NPB * HID];   // 8 KB
    __shared__ int degs[NPB];
    int tid = threadIdx.x;
    int lane = tid & 63, wid = tid >> 6;
    int b = blockIdx.x;

#pragma unroll
    for (int k = tid; k < NPB * HID; k += 256) acc[k] = 0.f;
    if (tid < NPB) degs[tid] = 0;
    __syncthreads();

    for (int r = 0; r < NREG; ++r) {
        int slot = r * NBUCK + b;
        int n = cnt[slot];
        if (n > CAP) n = CAP;
        const unsigned int* sp = stage + (size_t)slot * CAP;
        for (int i = wid; i < n; i += 4) {
            unsigned int u = sp[i];                 // same addr across wave -> broadcast
            int src = (int)(u >> 5);
            int dloc = (int)(u & 31);
            if (lane == 0) atomicAdd(&degs[dloc], 1);
            float v = bf2f(h[(size_t)src * HID + lane]);
            atomicAdd(&acc[dloc * HID + lane], v);  // ds_add_f32
        }
    }
    __syncthreads();

#pragma unroll
    for (int k = tid; k < NPB * HID; k += 256) {
        int dloc = k >> 6;
        int d = degs[dloc];
        float inv = d > 0 ? 1.f / (float)d : 0.f;
        out[(size_t)b * (NPB * HID) + k] = f2bf(acc[k] * inv);
    }
}

// ---------------------------------------------------------------------------
// head: out[i] = dot(h2[i,:], head_W) + head_b  (wave/node, shuffle reduce)
// ---------------------------------------------------------------------------
__global__ __launch_bounds__(256) void head_kernel(
    const unsigned short* __restrict__ h2, const float* __restrict__ hw,
    const float* __restrict__ hb, float* __restrict__ out) {
    int lane = threadIdx.x & 63;
    int node = (int)((blockIdx.x * blockDim.x + threadIdx.x) >> 6);
    if (node >= N_NODES) return;
    float v = bf2f(h2[(size_t)node * HID + lane]) * hw[lane];
#pragma unroll
    for (int d = 32; d > 0; d >>= 1) v += __shfl_xor(v, d);
    if (lane == 0) out[node] = v + hb[0];
}

extern "C" void kernel_launch(void* const* d_in, const int* in_sizes, int n_in,
                              void* d_out, int out_size, void* d_ws, size_t ws_size,
                              hipStream_t stream) {
    const float* x   = (const float*)d_in[0];
    const int*   ei  = (const int*)d_in[1];
    // d_in[2] = batch (unused)
    const float* fcW = (const float*)d_in[3];
    const float* fcb = (const float*)d_in[4];
    const float* Wl1 = (const float*)d_in[5];
    const float* bl1 = (const float*)d_in[6];
    const float* Wr1 = (const float*)d_in[7];
    const float* Wl2 = (const float*)d_in[8];
    const float* bl2 = (const float*)d_in[9];
    const float* Wr2 = (const float*)d_in[10];
    const float* hW  = (const float*)d_in[11];
    const float* hb  = (const float*)d_in[12];
    float* out = (float*)d_out;

    char* ws = (char*)d_ws;
    size_t off = 0;
    auto alloc = [&](size_t bytes) -> char* {
        char* p = ws + off;
        off = (off + bytes + 255) & ~(size_t)255;
        return p;
    };
    unsigned short* h0  = (unsigned short*)alloc((size_t)N_NODES * HID * 2);
    unsigned short* h1  = (unsigned short*)alloc((size_t)N_NODES * HID * 2);
    unsigned short* agg = (unsigned short*)alloc((size_t)N_NODES * HID * 2);
    unsigned int* stage = (unsigned int*)alloc((size_t)NREG * NBUCK * CAP * 4);  // 32 MB
    int* cnt            = (int*)alloc((size_t)NREG * NBUCK * 4);                 // 100 KB
    unsigned short* h2  = h0;  // h0 dead after sage1

    const int lin_blocks = (N_NODES / 16 + 3) / 4;
    const int edge_blocks = (N_EDGES + 255) / 256;
    const int node_wave_blocks = (N_NODES + 3) / 4;

    hipMemsetAsync(cnt, 0, (size_t)NREG * NBUCK * 4, stream);
    fc_kernel<<<lin_blocks, 256, 0, stream>>>(x, fcW, fcb, h0);
    bin_kernel<<<edge_blocks, 256, 0, stream>>>(ei, stage, cnt);
    agg_kernel<<<NBUCK, 256, 0, stream>>>(h0, stage, cnt, agg);
    sage_kernel<<<lin_blocks, 256, 0, stream>>>(agg, h0, Wl1, bl1, Wr1, h1, 1);
    agg_kernel<<<NBUCK, 256, 0, stream>>>(h1, stage, cnt, agg);
    sage_kernel<<<lin_blocks, 256, 0, stream>>>(agg, h1, Wl2, bl2, Wr2, h2, 0);
    head_kernel<<<node_wave_blocks, 256, 0, stream>>>(h2, hW, hb, out);
}

// Round 4
// 475.262 us; speedup vs baseline: 5.4216x; 5.4216x over previous
//
#include <hip/hip_runtime.h>

#define N_NODES 100000
#define N_EDGES 3200000
#define IN_DIM 128
#define HID 64

#define NPB 32                 // nodes per bucket
#define NBUCK (N_NODES / NPB)  // 3125, exact
#define NREG 8                 // stage regions (XCD proxy via blockIdx&7)
#define CAP 320                // slots per (region,bucket); mean 128, sd ~11
#define RAWCAP 1408            // max entries per bucket (mean 1024, sd 32 -> 12 sd)

typedef __attribute__((ext_vector_type(8))) short short8;
typedef __attribute__((ext_vector_type(4))) float f32x4;

__device__ inline float bf2f(unsigned short u) {
    union { unsigned int u; float f; } c;
    c.u = ((unsigned int)u) << 16;
    return c.f;
}
__device__ inline unsigned short f2bf(float f) {
    union { float f; unsigned int u; } c;
    c.f = f;
    unsigned int u = c.u;
    return (unsigned short)((u + 0x7fffu + ((u >> 16) & 1u)) >> 16);  // RNE
}
__device__ inline float asf(unsigned int u) {
    union { unsigned int u; float f; } c; c.u = u; return c.f;
}
// load 8 contiguous fp32, convert to bf16x8 MFMA fragment
__device__ inline short8 cvt8(const float* __restrict__ p) {
    f32x4 lo = *reinterpret_cast<const f32x4*>(p);
    f32x4 hi = *reinterpret_cast<const f32x4*>(p + 4);
    short8 r;
#pragma unroll
    for (int j = 0; j < 4; ++j) { r[j] = (short)f2bf(lo[j]); r[4 + j] = (short)f2bf(hi[j]); }
    return r;
}

// ---------------------------------------------------------------------------
// fc + relu: h0 = relu(x @ W^T + b), x:[N,128] fp32, W:[64,128] fp32, h0 bf16.
// ---------------------------------------------------------------------------
__global__ __launch_bounds__(256) void fc_kernel(
    const float* __restrict__ x, const float* __restrict__ W,
    const float* __restrict__ b, unsigned short* __restrict__ h0) {
    int lane = threadIdx.x & 63;
    int wtile = (int)((blockIdx.x * blockDim.x + threadIdx.x) >> 6);
    if (wtile >= N_NODES / 16) return;
    int col = lane & 15, quad = lane >> 4;

    short8 bw[4][4];
#pragma unroll
    for (int nt = 0; nt < 4; ++nt)
#pragma unroll
        for (int ks = 0; ks < 4; ++ks)
            bw[nt][ks] = cvt8(W + (nt * 16 + col) * IN_DIM + ks * 32 + quad * 8);

    f32x4 acc[4];
#pragma unroll
    for (int nt = 0; nt < 4; ++nt) acc[nt] = {0.f, 0.f, 0.f, 0.f};

    int node0 = wtile * 16;
    const float* xrow = x + (size_t)(node0 + col) * IN_DIM + quad * 8;
#pragma unroll
    for (int ks = 0; ks < 4; ++ks) {
        short8 a = cvt8(xrow + ks * 32);
#pragma unroll
        for (int nt = 0; nt < 4; ++nt)
            acc[nt] = __builtin_amdgcn_mfma_f32_16x16x32_bf16(a, bw[nt][ks], acc[nt], 0, 0, 0);
    }

#pragma unroll
    for (int nt = 0; nt < 4; ++nt) {
        float bias = b[nt * 16 + col];
#pragma unroll
        for (int r = 0; r < 4; ++r) {
            float v = acc[nt][r] + bias;
            v = v > 0.f ? v : 0.f;
            h0[(size_t)(node0 + quad * 4 + r) * HID + nt * 16 + col] = f2bf(v);
        }
    }
}

// ---------------------------------------------------------------------------
// SAGE linear: hout = (agg @ Wl^T + bl) + (hin @ Wr^T) [+relu]. agg/hin/hout bf16.
// ---------------------------------------------------------------------------
__global__ __launch_bounds__(256) void sage_kernel(
    const unsigned short* __restrict__ agg, const unsigned short* __restrict__ hin,
    const float* __restrict__ Wl, const float* __restrict__ bl,
    const float* __restrict__ Wr, unsigned short* __restrict__ hout, int do_relu) {
    int lane = threadIdx.x & 63;
    int wtile = (int)((blockIdx.x * blockDim.x + threadIdx.x) >> 6);
    if (wtile >= N_NODES / 16) return;
    int col = lane & 15, quad = lane >> 4;

    short8 bwl[4][2], bwr[4][2];
#pragma unroll
    for (int nt = 0; nt < 4; ++nt)
#pragma unroll
        for (int ks = 0; ks < 2; ++ks) {
            bwl[nt][ks] = cvt8(Wl + (nt * 16 + col) * HID + ks * 32 + quad * 8);
            bwr[nt][ks] = cvt8(Wr + (nt * 16 + col) * HID + ks * 32 + quad * 8);
        }

    f32x4 acc[4];
#pragma unroll
    for (int nt = 0; nt < 4; ++nt) acc[nt] = {0.f, 0.f, 0.f, 0.f};

    int node0 = wtile * 16;
    const unsigned short* arow = agg + (size_t)(node0 + col) * HID + quad * 8;
    const unsigned short* hrow = hin + (size_t)(node0 + col) * HID + quad * 8;
#pragma unroll
    for (int ks = 0; ks < 2; ++ks) {
        short8 aA = *reinterpret_cast<const short8*>(arow + ks * 32);
#pragma unroll
        for (int nt = 0; nt < 4; ++nt)
            acc[nt] = __builtin_amdgcn_mfma_f32_16x16x32_bf16(aA, bwl[nt][ks], acc[nt], 0, 0, 0);
        short8 aH = *reinterpret_cast<const short8*>(hrow + ks * 32);
#pragma unroll
        for (int nt = 0; nt < 4; ++nt)
            acc[nt] = __builtin_amdgcn_mfma_f32_16x16x32_bf16(aH, bwr[nt][ks], acc[nt], 0, 0, 0);
    }

#pragma unroll
    for (int nt = 0; nt < 4; ++nt) {
        float bias = bl[nt * 16 + col];
#pragma unroll
        for (int r = 0; r < 4; ++r) {
            float v = acc[nt][r] + bias;
            if (do_relu) v = v > 0.f ? v : 0.f;
            hout[(size_t)(node0 + quad * 4 + r) * HID + nt * 16 + col] = f2bf(v);
        }
    }
}

// ---------------------------------------------------------------------------
// Binning: edge -> packed (src<<5 | dst&31) appended to (region,bucket) slab.
// Region = blockIdx&7 keeps a slab's tail line hot in one XCD's L2.
// ---------------------------------------------------------------------------
__global__ __launch_bounds__(256) void bin_kernel(
    const int* __restrict__ ei, unsigned int* __restrict__ stage,
    int* __restrict__ cnt) {
    int e = blockIdx.x * blockDim.x + threadIdx.x;
    if (e >= N_EDGES) return;
    int dst = ei[N_EDGES + e];
    int src = ei[e];
    int b = dst >> 5;
    int r = blockIdx.x & (NREG - 1);
    int slot = r * NBUCK + b;
    int pos = atomicAdd(&cnt[slot], 1);
    if (pos < CAP) stage[(size_t)slot * CAP + pos] = ((unsigned int)src << 5) | (dst & 31);
}

// ---------------------------------------------------------------------------
// Bucket aggregation, latency-optimized:
//  P0: stage all (region,bucket) entries -> LDS raw[] (coalesced)
//  P1: 32-way LDS counting sort by dst-local -> sorted src lists + degrees
//  P2: register accumulation: wave = 8 nodes; 2 edges per instr (lane half =
//      edge, 32 lanes x uint = 2 bf16 feats), 4 loads in flight (8 edges).
// ---------------------------------------------------------------------------
__global__ __launch_bounds__(256) void agg_kernel(
    const unsigned short* __restrict__ h, const unsigned int* __restrict__ stage,
    const int* __restrict__ cnt, unsigned short* __restrict__ out) {
    __shared__ unsigned int raw[RAWCAP];
    __shared__ unsigned int srt[RAWCAP];
    __shared__ int seg_off[NREG + 1];
    __shared__ int cnt32[NPB], off32[NPB], pos32[NPB];
    int tid = threadIdx.x;
    int lane = tid & 63, wid = tid >> 6;
    int b = blockIdx.x;

    // P0a: region counts -> offsets
    if (tid == 0) {
        int r = 0;
        for (int j = 0; j < NREG; ++j) {
            seg_off[j] = r;
            int n = cnt[j * NBUCK + b];
            if (n > CAP) n = CAP;
            r += n;
            if (r > RAWCAP) r = RAWCAP;
        }
        seg_off[NREG] = r;
    }
    if (tid < NPB) cnt32[tid] = 0;
    __syncthreads();
    // P0b: coalesced copy of each region segment
    for (int r = 0; r < NREG; ++r) {
        int o = seg_off[r], n = seg_off[r + 1] - o;
        const unsigned int* sp = stage + (size_t)(r * NBUCK + b) * CAP;
        for (int i = tid; i < n; i += 256) raw[o + i] = sp[i];
    }
    __syncthreads();
    int total = seg_off[NREG];
    // P1: count, scan, scatter
    for (int i = tid; i < total; i += 256) atomicAdd(&cnt32[raw[i] & 31], 1);
    __syncthreads();
    if (tid == 0) {
        int r = 0;
        for (int j = 0; j < NPB; ++j) { off32[j] = r; pos32[j] = r; r += cnt32[j]; }
    }
    __syncthreads();
    for (int i = tid; i < total; i += 256) {
        unsigned int u = raw[i];
        int p = atomicAdd(&pos32[u & 31], 1);
        srt[p] = u >> 5;  // src node id
    }
    __syncthreads();

    // P2: wave wid handles nodes wid*8 .. wid*8+7
    int half = lane >> 5, off2 = lane & 31;
    const char* hb = (const char*)h;
#pragma unroll
    for (int k = 0; k < 8; ++k) {
        int d = wid * 8 + k;
        int s = off32[d], n = cnt32[d];
        float ax0 = 0.f, ay0 = 0.f, ax1 = 0.f, ay1 = 0.f;
        float ax2 = 0.f, ay2 = 0.f, ax3 = 0.f, ay3 = 0.f;
        int i = 0;
        for (; i + 8 <= n; i += 8) {
            unsigned int s0 = srt[s + i + 0 + half];
            unsigned int s1 = srt[s + i + 2 + half];
            unsigned int s2 = srt[s + i + 4 + half];
            unsigned int s3 = srt[s + i + 6 + half];
            unsigned int g0 = *(const unsigned int*)(hb + (size_t)s0 * 128 + off2 * 4);
            unsigned int g1 = *(const unsigned int*)(hb + (size_t)s1 * 128 + off2 * 4);
            unsigned int g2 = *(const unsigned int*)(hb + (size_t)s2 * 128 + off2 * 4);
            unsigned int g3 = *(const unsigned int*)(hb + (size_t)s3 * 128 + off2 * 4);
            ax0 += asf(g0 << 16); ay0 += asf(g0 & 0xffff0000u);
            ax1 += asf(g1 << 16); ay1 += asf(g1 & 0xffff0000u);
            ax2 += asf(g2 << 16); ay2 += asf(g2 & 0xffff0000u);
            ax3 += asf(g3 << 16); ay3 += asf(g3 & 0xffff0000u);
        }
        for (; i < n; i += 2) {
            int valid = (i + half) < n;
            unsigned int si = srt[valid ? (s + i + half) : s];
            unsigned int g = *(const unsigned int*)(hb + (size_t)si * 128 + off2 * 4);
            if (valid) { ax0 += asf(g << 16); ay0 += asf(g & 0xffff0000u); }
        }
        float ax = (ax0 + ax1) + (ax2 + ax3);
        float ay = (ay0 + ay1) + (ay2 + ay3);
        ax += __shfl_xor(ax, 32);
        ay += __shfl_xor(ay, 32);
        if (half == 0) {
            float inv = n > 0 ? 1.f / (float)n : 0.f;
            unsigned int pair = (unsigned int)f2bf(ax * inv) |
                                ((unsigned int)f2bf(ay * inv) << 16);
            ((unsigned int*)out)[((size_t)b * NPB + d) * 32 + off2] = pair;
        }
    }
}

// ---------------------------------------------------------------------------
// head: out[i] = dot(h2[i,:], head_W) + head_b  (wave/node, shuffle reduce)
// ---------------------------------------------------------------------------
__global__ __launch_bounds__(256) void head_kernel(
    const unsigned short* __restrict__ h2, const float* __restrict__ hw,
    const float* __restrict__ hb, float* __restrict__ out) {
    int lane = threadIdx.x & 63;
    int node = (int)((blockIdx.x * blockDim.x + threadIdx.x) >> 6);
    if (node >= N_NODES) return;
    float v = bf2f(h2[(size_t)node * HID + lane]) * hw[lane];
#pragma unroll
    for (int d = 32; d > 0; d >>= 1) v += __shfl_xor(v, d);
    if (lane == 0) out[node] = v + hb[0];
}

extern "C" void kernel_launch(void* const* d_in, const int* in_sizes, int n_in,
                              void* d_out, int out_size, void* d_ws, size_t ws_size,
                              hipStream_t stream) {
    const float* x   = (const float*)d_in[0];
    const int*   ei  = (const int*)d_in[1];
    // d_in[2] = batch (unused)
    const float* fcW = (const float*)d_in[3];
    const float* fcb = (const float*)d_in[4];
    const float* Wl1 = (const float*)d_in[5];
    const float* bl1 = (const float*)d_in[6];
    const float* Wr1 = (const float*)d_in[7];
    const float* Wl2 = (const float*)d_in[8];
    const float* bl2 = (const float*)d_in[9];
    const float* Wr2 = (const float*)d_in[10];
    const float* hW  = (const float*)d_in[11];
    const float* hb  = (const float*)d_in[12];
    float* out = (float*)d_out;

    char* ws = (char*)d_ws;
    size_t off = 0;
    auto alloc = [&](size_t bytes) -> char* {
        char* p = ws + off;
        off = (off + bytes + 255) & ~(size_t)255;
        return p;
    };
    unsigned short* h0  = (unsigned short*)alloc((size_t)N_NODES * HID * 2);
    unsigned short* h1  = (unsigned short*)alloc((size_t)N_NODES * HID * 2);
    unsigned short* agg = (unsigned short*)alloc((size_t)N_NODES * HID * 2);
    unsigned int* stage = (unsigned int*)alloc((size_t)NREG * NBUCK * CAP * 4);  // 32 MB
    int* cnt            = (int*)alloc((size_t)NREG * NBUCK * 4);                 // 100 KB
    unsigned short* h2  = h0;  // h0 dead after sage1

    const int lin_blocks = (N_NODES / 16 + 3) / 4;
    const int edge_blocks = (N_EDGES + 255) / 256;
    const int node_wave_blocks = (N_NODES + 3) / 4;

    hipMemsetAsync(cnt, 0, (size_t)NREG * NBUCK * 4, stream);
    fc_kernel<<<lin_blocks, 256, 0, stream>>>(x, fcW, fcb, h0);
    bin_kernel<<<edge_blocks, 256, 0, stream>>>(ei, stage, cnt);
    agg_kernel<<<NBUCK, 256, 0, stream>>>(h0, stage, cnt, agg);
    sage_kernel<<<lin_blocks, 256, 0, stream>>>(agg, h0, Wl1, bl1, Wr1, h1, 1);
    agg_kernel<<<NBUCK, 256, 0, stream>>>(h1, stage, cnt, agg);
    sage_kernel<<<lin_blocks, 256, 0, stream>>>(agg, h1, Wl2, bl2, Wr2, h2, 0);
    head_kernel<<<node_wave_blocks, 256, 0, stream>>>(h2, hW, hb, out);
}

// Round 5
// 462.969 us; speedup vs baseline: 5.5656x; 1.0266x over previous
//
#include <hip/hip_runtime.h>

#define N_NODES 100000
#define N_EDGES 3200000
#define IN_DIM 128
#define HID 64

#define NPB 32                 // nodes per bucket
#define NBUCK (N_NODES / NPB)  // 3125, exact
#define NREG 8                 // stage regions = XCD id (perf heuristic only)
#define CAP 448                // slots per (region,bucket); mean 128 if balanced
#define RAWCAP 1408            // max entries per bucket (mean 1024, sd 32 -> 12 sd)

typedef __attribute__((ext_vector_type(8))) short short8;
typedef __attribute__((ext_vector_type(4))) float f32x4;

__device__ inline float bf2f(unsigned short u) {
    union { unsigned int u; float f; } c;
    c.u = ((unsigned int)u) << 16;
    return c.f;
}
__device__ inline unsigned short f2bf(float f) {
    union { float f; unsigned int u; } c;
    c.f = f;
    unsigned int u = c.u;
    return (unsigned short)((u + 0x7fffu + ((u >> 16) & 1u)) >> 16);  // RNE
}
__device__ inline float asf(unsigned int u) {
    union { unsigned int u; float f; } c; c.u = u; return c.f;
}
// load 8 contiguous fp32, convert to bf16x8 MFMA fragment
__device__ inline short8 cvt8(const float* __restrict__ p) {
    f32x4 lo = *reinterpret_cast<const f32x4*>(p);
    f32x4 hi = *reinterpret_cast<const f32x4*>(p + 4);
    short8 r;
#pragma unroll
    for (int j = 0; j < 4; ++j) { r[j] = (short)f2bf(lo[j]); r[4 + j] = (short)f2bf(hi[j]); }
    return r;
}

// ---------------------------------------------------------------------------
// fc + relu: h0 = relu(x @ W^T + b), x:[N,128] fp32, W:[64,128] fp32, h0 bf16.
// ---------------------------------------------------------------------------
__global__ __launch_bounds__(256) void fc_kernel(
    const float* __restrict__ x, const float* __restrict__ W,
    const float* __restrict__ b, unsigned short* __restrict__ h0) {
    int lane = threadIdx.x & 63;
    int wtile = (int)((blockIdx.x * blockDim.x + threadIdx.x) >> 6);
    if (wtile >= N_NODES / 16) return;
    int col = lane & 15, quad = lane >> 4;

    short8 bw[4][4];
#pragma unroll
    for (int nt = 0; nt < 4; ++nt)
#pragma unroll
        for (int ks = 0; ks < 4; ++ks)
            bw[nt][ks] = cvt8(W + (nt * 16 + col) * IN_DIM + ks * 32 + quad * 8);

    f32x4 acc[4];
#pragma unroll
    for (int nt = 0; nt < 4; ++nt) acc[nt] = {0.f, 0.f, 0.f, 0.f};

    int node0 = wtile * 16;
    const float* xrow = x + (size_t)(node0 + col) * IN_DIM + quad * 8;
#pragma unroll
    for (int ks = 0; ks < 4; ++ks) {
        short8 a = cvt8(xrow + ks * 32);
#pragma unroll
        for (int nt = 0; nt < 4; ++nt)
            acc[nt] = __builtin_amdgcn_mfma_f32_16x16x32_bf16(a, bw[nt][ks], acc[nt], 0, 0, 0);
    }

#pragma unroll
    for (int nt = 0; nt < 4; ++nt) {
        float bias = b[nt * 16 + col];
#pragma unroll
        for (int r = 0; r < 4; ++r) {
            float v = acc[nt][r] + bias;
            v = v > 0.f ? v : 0.f;
            h0[(size_t)(node0 + quad * 4 + r) * HID + nt * 16 + col] = f2bf(v);
        }
    }
}

// ---------------------------------------------------------------------------
// SAGE linear: t = (agg @ Wl^T + bl) + (hin @ Wr^T).
//   do_head==0: hout = relu(t) (bf16)
//   do_head==1: out[node] = dot(t[node,:], hw) + hb0 (fused head, fp32 out;
//               skips materializing h2 -> saves 25.6 MB traffic + rounding)
// ---------------------------------------------------------------------------
__global__ __launch_bounds__(256) void sage_kernel(
    const unsigned short* __restrict__ agg, const unsigned short* __restrict__ hin,
    const float* __restrict__ Wl, const float* __restrict__ bl,
    const float* __restrict__ Wr, unsigned short* __restrict__ hout,
    const float* __restrict__ hw, const float* __restrict__ hbias,
    float* __restrict__ head_out, int do_head) {
    int lane = threadIdx.x & 63;
    int wtile = (int)((blockIdx.x * blockDim.x + threadIdx.x) >> 6);
    if (wtile >= N_NODES / 16) return;
    int col = lane & 15, quad = lane >> 4;

    short8 bwl[4][2], bwr[4][2];
#pragma unroll
    for (int nt = 0; nt < 4; ++nt)
#pragma unroll
        for (int ks = 0; ks < 2; ++ks) {
            bwl[nt][ks] = cvt8(Wl + (nt * 16 + col) * HID + ks * 32 + quad * 8);
            bwr[nt][ks] = cvt8(Wr + (nt * 16 + col) * HID + ks * 32 + quad * 8);
        }

    f32x4 acc[4];
#pragma unroll
    for (int nt = 0; nt < 4; ++nt) acc[nt] = {0.f, 0.f, 0.f, 0.f};

    int node0 = wtile * 16;
    const unsigned short* arow = agg + (size_t)(node0 + col) * HID + quad * 8;
    const unsigned short* hrow = hin + (size_t)(node0 + col) * HID + quad * 8;
#pragma unroll
    for (int ks = 0; ks < 2; ++ks) {
        short8 aA = *reinterpret_cast<const short8*>(arow + ks * 32);
#pragma unroll
        for (int nt = 0; nt < 4; ++nt)
            acc[nt] = __builtin_amdgcn_mfma_f32_16x16x32_bf16(aA, bwl[nt][ks], acc[nt], 0, 0, 0);
        short8 aH = *reinterpret_cast<const short8*>(hrow + ks * 32);
#pragma unroll
        for (int nt = 0; nt < 4; ++nt)
            acc[nt] = __builtin_amdgcn_mfma_f32_16x16x32_bf16(aH, bwr[nt][ks], acc[nt], 0, 0, 0);
    }

    if (!do_head) {
#pragma unroll
        for (int nt = 0; nt < 4; ++nt) {
            float bias = bl[nt * 16 + col];
#pragma unroll
            for (int r = 0; r < 4; ++r) {
                float v = acc[nt][r] + bias;
                v = v > 0.f ? v : 0.f;
                hout[(size_t)(node0 + quad * 4 + r) * HID + nt * 16 + col] = f2bf(v);
            }
        }
    } else {
        float hb0 = hbias[0];
        float vr[4] = {0.f, 0.f, 0.f, 0.f};
#pragma unroll
        for (int nt = 0; nt < 4; ++nt) {
            int f = nt * 16 + col;
            float w = hw[f], bias = bl[f];
#pragma unroll
            for (int r = 0; r < 4; ++r) vr[r] += (acc[nt][r] + bias) * w;
        }
#pragma unroll
        for (int r = 0; r < 4; ++r) {
#pragma unroll
            for (int d = 1; d < 16; d <<= 1) vr[r] += __shfl_xor(vr[r], d);
        }
        if (col == 0) {
#pragma unroll
            for (int r = 0; r < 4; ++r)
                head_out[node0 + quad * 4 + r] = vr[r] + hb0;
        }
    }
}

// ---------------------------------------------------------------------------
// Binning: edge -> packed (src<<5 | dst&31) appended to (region,bucket) slab.
// Region = HW XCC_ID: all writers of a slab tail line share one XCD's L2, so
// 4B appends merge in-cache and writeback ~= payload (perf-only heuristic;
// any region value is functionally correct).
// ---------------------------------------------------------------------------
__global__ __launch_bounds__(256) void bin_kernel(
    const int* __restrict__ ei, unsigned int* __restrict__ stage,
    int* __restrict__ cnt) {
    int e = blockIdx.x * blockDim.x + threadIdx.x;
    if (e >= N_EDGES) return;
    unsigned int xcc;
    asm volatile("s_getreg_b32 %0, hwreg(HW_REG_XCC_ID)" : "=s"(xcc));
    int r = (int)(xcc & (NREG - 1));
    int dst = ei[N_EDGES + e];
    int src = ei[e];
    int b = dst >> 5;
    int slot = r * NBUCK + b;
    int pos = atomicAdd(&cnt[slot], 1);
    if (pos < CAP) stage[(size_t)slot * CAP + pos] = ((unsigned int)src << 5) | (dst & 31);
}

// ---------------------------------------------------------------------------
// Bucket aggregation:
//  P0: stage all (region,bucket) entries -> LDS raw[] (coalesced)
//  P1: 32-way LDS counting sort by dst-local -> sorted src lists + degrees
//  P2: register accumulation: wave = 8 nodes; 2 edges per instr (lane half =
//      edge, 32 lanes x uint = 2 bf16 feats), 4 loads in flight (8 edges).
// ---------------------------------------------------------------------------
__global__ __launch_bounds__(256) void agg_kernel(
    const unsigned short* __restrict__ h, const unsigned int* __restrict__ stage,
    const int* __restrict__ cnt, unsigned short* __restrict__ out) {
    __shared__ unsigned int raw[RAWCAP];
    __shared__ unsigned int srt[RAWCAP];
    __shared__ int seg_off[NREG + 1];
    __shared__ int cnt32[NPB], off32[NPB], pos32[NPB];
    int tid = threadIdx.x;
    int lane = tid & 63, wid = tid >> 6;
    int b = blockIdx.x;

    if (tid == 0) {
        int r = 0;
        for (int j = 0; j < NREG; ++j) {
            seg_off[j] = r;
            int n = cnt[j * NBUCK + b];
            if (n > CAP) n = CAP;
            r += n;
            if (r > RAWCAP) r = RAWCAP;
        }
        seg_off[NREG] = r;
    }
    if (tid < NPB) cnt32[tid] = 0;
    __syncthreads();
    for (int r = 0; r < NREG; ++r) {
        int o = seg_off[r], n = seg_off[r + 1] - o;
        const unsigned int* sp = stage + (size_t)(r * NBUCK + b) * CAP;
        for (int i = tid; i < n; i += 256) raw[o + i] = sp[i];
    }
    __syncthreads();
    int total = seg_off[NREG];
    for (int i = tid; i < total; i += 256) atomicAdd(&cnt32[raw[i] & 31], 1);
    __syncthreads();
    if (tid == 0) {
        int r = 0;
        for (int j = 0; j < NPB; ++j) { off32[j] = r; pos32[j] = r; r += cnt32[j]; }
    }
    __syncthreads();
    for (int i = tid; i < total; i += 256) {
        unsigned int u = raw[i];
        int p = atomicAdd(&pos32[u & 31], 1);
        srt[p] = u >> 5;  // src node id
    }
    __syncthreads();

    // P2: wave wid handles nodes wid*8 .. wid*8+7
    int half = lane >> 5, off2 = lane & 31;
    const char* hbp = (const char*)h;
#pragma unroll
    for (int k = 0; k < 8; ++k) {
        int d = wid * 8 + k;
        int s = off32[d], n = cnt32[d];
        float ax0 = 0.f, ay0 = 0.f, ax1 = 0.f, ay1 = 0.f;
        float ax2 = 0.f, ay2 = 0.f, ax3 = 0.f, ay3 = 0.f;
        int i = 0;
        for (; i + 8 <= n; i += 8) {
            unsigned int s0 = srt[s + i + 0 + half];
            unsigned int s1 = srt[s + i + 2 + half];
            unsigned int s2 = srt[s + i + 4 + half];
            unsigned int s3 = srt[s + i + 6 + half];
            unsigned int g0 = *(const unsigned int*)(hbp + (size_t)s0 * 128 + off2 * 4);
            unsigned int g1 = *(const unsigned int*)(hbp + (size_t)s1 * 128 + off2 * 4);
            unsigned int g2 = *(const unsigned int*)(hbp + (size_t)s2 * 128 + off2 * 4);
            unsigned int g3 = *(const unsigned int*)(hbp + (size_t)s3 * 128 + off2 * 4);
            ax0 += asf(g0 << 16); ay0 += asf(g0 & 0xffff0000u);
            ax1 += asf(g1 << 16); ay1 += asf(g1 & 0xffff0000u);
            ax2 += asf(g2 << 16); ay2 += asf(g2 & 0xffff0000u);
            ax3 += asf(g3 << 16); ay3 += asf(g3 & 0xffff0000u);
        }
        for (; i < n; i += 2) {
            int valid = (i + half) < n;
            unsigned int si = srt[valid ? (s + i + half) : s];
            unsigned int g = *(const unsigned int*)(hbp + (size_t)si * 128 + off2 * 4);
            if (valid) { ax0 += asf(g << 16); ay0 += asf(g & 0xffff0000u); }
        }
        float ax = (ax0 + ax1) + (ax2 + ax3);
        float ay = (ay0 + ay1) + (ay2 + ay3);
        ax += __shfl_xor(ax, 32);
        ay += __shfl_xor(ay, 32);
        if (half == 0) {
            float inv = n > 0 ? 1.f / (float)n : 0.f;
            unsigned int pair = (unsigned int)f2bf(ax * inv) |
                                ((unsigned int)f2bf(ay * inv) << 16);
            ((unsigned int*)out)[((size_t)b * NPB + d) * 32 + off2] = pair;
        }
    }
}

extern "C" void kernel_launch(void* const* d_in, const int* in_sizes, int n_in,
                              void* d_out, int out_size, void* d_ws, size_t ws_size,
                              hipStream_t stream) {
    const float* x   = (const float*)d_in[0];
    const int*   ei  = (const int*)d_in[1];
    // d_in[2] = batch (unused)
    const float* fcW = (const float*)d_in[3];
    const float* fcb = (const float*)d_in[4];
    const float* Wl1 = (const float*)d_in[5];
    const float* bl1 = (const float*)d_in[6];
    const float* Wr1 = (const float*)d_in[7];
    const float* Wl2 = (const float*)d_in[8];
    const float* bl2 = (const float*)d_in[9];
    const float* Wr2 = (const float*)d_in[10];
    const float* hW  = (const float*)d_in[11];
    const float* hb  = (const float*)d_in[12];
    float* out = (float*)d_out;

    char* ws = (char*)d_ws;
    size_t off = 0;
    auto alloc = [&](size_t bytes) -> char* {
        char* p = ws + off;
        off = (off + bytes + 255) & ~(size_t)255;
        return p;
    };
    unsigned short* h0  = (unsigned short*)alloc((size_t)N_NODES * HID * 2);
    unsigned short* h1  = (unsigned short*)alloc((size_t)N_NODES * HID * 2);
    unsigned short* agg = (unsigned short*)alloc((size_t)N_NODES * HID * 2);
    unsigned int* stage = (unsigned int*)alloc((size_t)NREG * NBUCK * CAP * 4);  // 44.8 MB
    int* cnt            = (int*)alloc((size_t)NREG * NBUCK * 4);                 // 100 KB

    const int lin_blocks = (N_NODES / 16 + 3) / 4;
    const int edge_blocks = (N_EDGES + 255) / 256;

    hipMemsetAsync(cnt, 0, (size_t)NREG * NBUCK * 4, stream);
    fc_kernel<<<lin_blocks, 256, 0, stream>>>(x, fcW, fcb, h0);
    bin_kernel<<<edge_blocks, 256, 0, stream>>>(ei, stage, cnt);
    agg_kernel<<<NBUCK, 256, 0, stream>>>(h0, stage, cnt, agg);
    sage_kernel<<<lin_blocks, 256, 0, stream>>>(agg, h0, Wl1, bl1, Wr1, h1,
                                                nullptr, nullptr, nullptr, 0);
    agg_kernel<<<NBUCK, 256, 0, stream>>>(h1, stage, cnt, agg);
    sage_kernel<<<lin_blocks, 256, 0, stream>>>(agg, h1, Wl2, bl2, Wr2, nullptr,
                                                hW, hb, out, 1);
}

// Round 6
// 396.751 us; speedup vs baseline: 6.4945x; 1.1669x over previous
//
#include <hip/hip_runtime.h>

#define N_NODES 100000
#define N_EDGES 3200000
#define IN_DIM 128
#define HID 64

#define NPB 32                  // nodes per bucket
#define NBUCK 3125              // N_NODES / NPB, exact
#define NBUCKP 3328             // padded to 256*13 for the block scan
#define TILE 12800              // edges per bin block; 3.2M / 12800 = 250 exact
#define NSEG 250                // number of bin blocks / segments
#define RAWCAP 1408             // max entries per bucket (mean 1024, sd 32)

typedef __attribute__((ext_vector_type(8))) short short8;
typedef __attribute__((ext_vector_type(4))) float f32x4;

__device__ inline float bf2f(unsigned short u) {
    union { unsigned int u; float f; } c;
    c.u = ((unsigned int)u) << 16;
    return c.f;
}
__device__ inline unsigned short f2bf(float f) {
    union { float f; unsigned int u; } c;
    c.f = f;
    unsigned int u = c.u;
    return (unsigned short)((u + 0x7fffu + ((u >> 16) & 1u)) >> 16);  // RNE
}
__device__ inline float asf(unsigned int u) {
    union { unsigned int u; float f; } c; c.u = u; return c.f;
}
// load 8 contiguous fp32, convert to bf16x8 MFMA fragment
__device__ inline short8 cvt8(const float* __restrict__ p) {
    f32x4 lo = *reinterpret_cast<const f32x4*>(p);
    f32x4 hi = *reinterpret_cast<const f32x4*>(p + 4);
    short8 r;
#pragma unroll
    for (int j = 0; j < 4; ++j) { r[j] = (short)f2bf(lo[j]); r[4 + j] = (short)f2bf(hi[j]); }
    return r;
}

// ---------------------------------------------------------------------------
// fc + relu: h0 = relu(x @ W^T + b), x:[N,128] fp32, W:[64,128] fp32, h0 bf16.
// ---------------------------------------------------------------------------
__global__ __launch_bounds__(256) void fc_kernel(
    const float* __restrict__ x, const float* __restrict__ W,
    const float* __restrict__ b, unsigned short* __restrict__ h0) {
    int lane = threadIdx.x & 63;
    int wtile = (int)((blockIdx.x * blockDim.x + threadIdx.x) >> 6);
    if (wtile >= N_NODES / 16) return;
    int col = lane & 15, quad = lane >> 4;

    short8 bw[4][4];
#pragma unroll
    for (int nt = 0; nt < 4; ++nt)
#pragma unroll
        for (int ks = 0; ks < 4; ++ks)
            bw[nt][ks] = cvt8(W + (nt * 16 + col) * IN_DIM + ks * 32 + quad * 8);

    f32x4 acc[4];
#pragma unroll
    for (int nt = 0; nt < 4; ++nt) acc[nt] = {0.f, 0.f, 0.f, 0.f};

    int node0 = wtile * 16;
    const float* xrow = x + (size_t)(node0 + col) * IN_DIM + quad * 8;
#pragma unroll
    for (int ks = 0; ks < 4; ++ks) {
        short8 a = cvt8(xrow + ks * 32);
#pragma unroll
        for (int nt = 0; nt < 4; ++nt)
            acc[nt] = __builtin_amdgcn_mfma_f32_16x16x32_bf16(a, bw[nt][ks], acc[nt], 0, 0, 0);
    }

#pragma unroll
    for (int nt = 0; nt < 4; ++nt) {
        float bias = b[nt * 16 + col];
#pragma unroll
        for (int r = 0; r < 4; ++r) {
            float v = acc[nt][r] + bias;
            v = v > 0.f ? v : 0.f;
            h0[(size_t)(node0 + quad * 4 + r) * HID + nt * 16 + col] = f2bf(v);
        }
    }
}

// ---------------------------------------------------------------------------
// SAGE linear: t = (agg @ Wl^T + bl) + (hin @ Wr^T).
//   do_head==0: hout = relu(t) (bf16)
//   do_head==1: out[node] = dot(t[node,:], hw) + hb0 (fused head, fp32 out)
// ---------------------------------------------------------------------------
__global__ __launch_bounds__(256) void sage_kernel(
    const unsigned short* __restrict__ agg, const unsigned short* __restrict__ hin,
    const float* __restrict__ Wl, const float* __restrict__ bl,
    const float* __restrict__ Wr, unsigned short* __restrict__ hout,
    const float* __restrict__ hw, const float* __restrict__ hbias,
    float* __restrict__ head_out, int do_head) {
    int lane = threadIdx.x & 63;
    int wtile = (int)((blockIdx.x * blockDim.x + threadIdx.x) >> 6);
    if (wtile >= N_NODES / 16) return;
    int col = lane & 15, quad = lane >> 4;

    short8 bwl[4][2], bwr[4][2];
#pragma unroll
    for (int nt = 0; nt < 4; ++nt)
#pragma unroll
        for (int ks = 0; ks < 2; ++ks) {
            bwl[nt][ks] = cvt8(Wl + (nt * 16 + col) * HID + ks * 32 + quad * 8);
            bwr[nt][ks] = cvt8(Wr + (nt * 16 + col) * HID + ks * 32 + quad * 8);
        }

    f32x4 acc[4];
#pragma unroll
    for (int nt = 0; nt < 4; ++nt) acc[nt] = {0.f, 0.f, 0.f, 0.f};

    int node0 = wtile * 16;
    const unsigned short* arow = agg + (size_t)(node0 + col) * HID + quad * 8;
    const unsigned short* hrow = hin + (size_t)(node0 + col) * HID + quad * 8;
#pragma unroll
    for (int ks = 0; ks < 2; ++ks) {
        short8 aA = *reinterpret_cast<const short8*>(arow + ks * 32);
#pragma unroll
        for (int nt = 0; nt < 4; ++nt)
            acc[nt] = __builtin_amdgcn_mfma_f32_16x16x32_bf16(aA, bwl[nt][ks], acc[nt], 0, 0, 0);
        short8 aH = *reinterpret_cast<const short8*>(hrow + ks * 32);
#pragma unroll
        for (int nt = 0; nt < 4; ++nt)
            acc[nt] = __builtin_amdgcn_mfma_f32_16x16x32_bf16(aH, bwr[nt][ks], acc[nt], 0, 0, 0);
    }

    if (!do_head) {
#pragma unroll
        for (int nt = 0; nt < 4; ++nt) {
            float bias = bl[nt * 16 + col];
#pragma unroll
            for (int r = 0; r < 4; ++r) {
                float v = acc[nt][r] + bias;
                v = v > 0.f ? v : 0.f;
                hout[(size_t)(node0 + quad * 4 + r) * HID + nt * 16 + col] = f2bf(v);
            }
        }
    } else {
        float hb0 = hbias[0];
        float vr[4] = {0.f, 0.f, 0.f, 0.f};
#pragma unroll
        for (int nt = 0; nt < 4; ++nt) {
            int f = nt * 16 + col;
            float w = hw[f], bias = bl[f];
#pragma unroll
            for (int r = 0; r < 4; ++r) vr[r] += (acc[nt][r] + bias) * w;
        }
#pragma unroll
        for (int r = 0; r < 4; ++r) {
#pragma unroll
            for (int d = 1; d < 16; d <<= 1) vr[r] += __shfl_xor(vr[r], d);
        }
        if (col == 0) {
#pragma unroll
            for (int r = 0; r < 4; ++r)
                head_out[node0 + quad * 4 + r] = vr[r] + hb0;
        }
    }
}

// ---------------------------------------------------------------------------
// Zero-atomic binning: block = private 12800-edge tile -> private stage segment.
//  A: LDS histogram over buckets (dst>>5)
//  B: block-wide exclusive scan (256 thr x 13 buckets) -> offs table (global)
//  C: re-read tile, scatter packed (src<<5|dst&31) into stage[blk*TILE + pos],
//     pos from LDS-atomic bump. Single-writer region -> merges in local L2.
// No global atomics anywhere.
// ---------------------------------------------------------------------------
__global__ __launch_bounds__(256) void bin_kernel(
    const int* __restrict__ ei, unsigned int* __restrict__ stage,
    int* __restrict__ offs) {
    __shared__ int hoff[NBUCKP];   // histogram, then running offsets
    __shared__ int wsum[4];
    int tid = threadIdx.x;
    int lane = tid & 63, wid = tid >> 6;
    int blk = blockIdx.x;
    int e0 = blk * TILE;

    for (int i = tid; i < NBUCKP; i += 256) hoff[i] = 0;
    __syncthreads();

    // A: histogram of dst buckets
    for (int it = 0; it < TILE / 256; ++it) {
        int dst = ei[(size_t)N_EDGES + e0 + it * 256 + tid];
        atomicAdd(&hoff[dst >> 5], 1);
    }
    __syncthreads();

    // B: exclusive scan of hoff[0..NBUCKP), 13 buckets per thread
    int base = tid * 13;
    int vals[13];
    int s = 0;
#pragma unroll
    for (int j = 0; j < 13; ++j) { vals[j] = s; s += hoff[base + j]; }
    int inc = s;
#pragma unroll
    for (int d = 1; d < 64; d <<= 1) {
        int n = __shfl_up(inc, d);
        if (lane >= d) inc += n;
    }
    int wave_excl = inc - s;
    if (lane == 63) wsum[wid] = inc;
    __syncthreads();
    if (tid == 0) {
        int r = 0;
#pragma unroll
        for (int w = 0; w < 4; ++w) { int t = wsum[w]; wsum[w] = r; r += t; }
    }
    __syncthreads();
    int tbase = wsum[wid] + wave_excl;
    __syncthreads();  // all reads of hoff done before overwrite
#pragma unroll
    for (int j = 0; j < 13; ++j) hoff[base + j] = tbase + vals[j];
    __syncthreads();

    // write offsets table (coalesced)
    int* og = offs + (size_t)blk * NBUCKP;
    for (int i = tid; i < NBUCKP; i += 256) og[i] = hoff[i];
    __syncthreads();

    // C: scatter into private stage segment
    unsigned int* sg = stage + (size_t)blk * TILE;
    for (int it = 0; it < TILE / 256; ++it) {
        int idx = e0 + it * 256 + tid;
        int src = ei[idx];
        int dst = ei[(size_t)N_EDGES + idx];
        int pos = atomicAdd(&hoff[dst >> 5], 1);
        sg[pos] = ((unsigned int)src << 5) | (unsigned int)(dst & 31);
    }
}

// ---------------------------------------------------------------------------
// Bucket aggregation:
//  P0: gather this bucket's entries from the 250 per-block segments -> LDS raw
//  P1: 32-way LDS counting sort by dst-local -> per-node src lists + degrees
//  P2: register accumulation: wave = 8 nodes; 2 edges per instr (lane half =
//      edge, 32 lanes x uint = 2 bf16 feats), 4 loads in flight (8 edges).
// ---------------------------------------------------------------------------
__global__ __launch_bounds__(256) void agg_kernel(
    const unsigned short* __restrict__ h, const unsigned int* __restrict__ stage,
    const int* __restrict__ offs, unsigned short* __restrict__ out) {
    __shared__ unsigned int raw[RAWCAP];
    __shared__ unsigned int srt[RAWCAP];
    __shared__ int cnt32[NPB], off32[NPB], pos32[NPB];
    __shared__ int seg_alloc;
    int tid = threadIdx.x;
    int lane = tid & 63, wid = tid >> 6;
    int b = blockIdx.x;

    if (tid == 0) seg_alloc = 0;
    if (tid < NPB) cnt32[tid] = 0;
    __syncthreads();

    // P0: per-thread segment copy (250 segments, ~4 entries each)
    if (tid < NSEG) {
        const int* ob = offs + (size_t)tid * NBUCKP + b;
        int s2 = ob[0], e2 = ob[1];
        int n = e2 - s2;
        if (n > 0) {
            int p = atomicAdd(&seg_alloc, n);
            if (p + n > RAWCAP) n = (RAWCAP > p) ? (RAWCAP - p) : 0;
            const unsigned int* sp = stage + (size_t)tid * TILE + s2;
            for (int i = 0; i < n; ++i) raw[p + i] = sp[i];
        }
    }
    __syncthreads();
    int total = seg_alloc;
    if (total > RAWCAP) total = RAWCAP;

    // P1: counting sort by dst-local
    for (int i = tid; i < total; i += 256) atomicAdd(&cnt32[raw[i] & 31], 1);
    __syncthreads();
    if (tid == 0) {
        int r = 0;
        for (int j = 0; j < NPB; ++j) { off32[j] = r; pos32[j] = r; r += cnt32[j]; }
    }
    __syncthreads();
    for (int i = tid; i < total; i += 256) {
        unsigned int u = raw[i];
        int p = atomicAdd(&pos32[u & 31], 1);
        srt[p] = u >> 5;  // src node id
    }
    __syncthreads();

    // P2: wave wid handles nodes wid*8 .. wid*8+7
    int half = lane >> 5, off2 = lane & 31;
    const char* hbp = (const char*)h;
#pragma unroll
    for (int k = 0; k < 8; ++k) {
        int d = wid * 8 + k;
        int s = off32[d], n = cnt32[d];
        float ax0 = 0.f, ay0 = 0.f, ax1 = 0.f, ay1 = 0.f;
        float ax2 = 0.f, ay2 = 0.f, ax3 = 0.f, ay3 = 0.f;
        int i = 0;
        for (; i + 8 <= n; i += 8) {
            unsigned int s0 = srt[s + i + 0 + half];
            unsigned int s1 = srt[s + i + 2 + half];
            unsigned int s2 = srt[s + i + 4 + half];
            unsigned int s3 = srt[s + i + 6 + half];
            unsigned int g0 = *(const unsigned int*)(hbp + (size_t)s0 * 128 + off2 * 4);
            unsigned int g1 = *(const unsigned int*)(hbp + (size_t)s1 * 128 + off2 * 4);
            unsigned int g2 = *(const unsigned int*)(hbp + (size_t)s2 * 128 + off2 * 4);
            unsigned int g3 = *(const unsigned int*)(hbp + (size_t)s3 * 128 + off2 * 4);
            ax0 += asf(g0 << 16); ay0 += asf(g0 & 0xffff0000u);
            ax1 += asf(g1 << 16); ay1 += asf(g1 & 0xffff0000u);
            ax2 += asf(g2 << 16); ay2 += asf(g2 & 0xffff0000u);
            ax3 += asf(g3 << 16); ay3 += asf(g3 & 0xffff0000u);
        }
        for (; i < n; i += 2) {
            int valid = (i + half) < n;
            unsigned int si = srt[valid ? (s + i + half) : s];
            unsigned int g = *(const unsigned int*)(hbp + (size_t)si * 128 + off2 * 4);
            if (valid) { ax0 += asf(g << 16); ay0 += asf(g & 0xffff0000u); }
        }
        float ax = (ax0 + ax1) + (ax2 + ax3);
        float ay = (ay0 + ay1) + (ay2 + ay3);
        ax += __shfl_xor(ax, 32);
        ay += __shfl_xor(ay, 32);
        if (half == 0) {
            float inv = n > 0 ? 1.f / (float)n : 0.f;
            unsigned int pair = (unsigned int)f2bf(ax * inv) |
                                ((unsigned int)f2bf(ay * inv) << 16);
            ((unsigned int*)out)[((size_t)b * NPB + d) * 32 + off2] = pair;
        }
    }
}

extern "C" void kernel_launch(void* const* d_in, const int* in_sizes, int n_in,
                              void* d_out, int out_size, void* d_ws, size_t ws_size,
                              hipStream_t stream) {
    const float* x   = (const float*)d_in[0];
    const int*   ei  = (const int*)d_in[1];
    // d_in[2] = batch (unused)
    const float* fcW = (const float*)d_in[3];
    const float* fcb = (const float*)d_in[4];
    const float* Wl1 = (const float*)d_in[5];
    const float* bl1 = (const float*)d_in[6];
    const float* Wr1 = (const float*)d_in[7];
    const float* Wl2 = (const float*)d_in[8];
    const float* bl2 = (const float*)d_in[9];
    const float* Wr2 = (const float*)d_in[10];
    const float* hW  = (const float*)d_in[11];
    const float* hb  = (const float*)d_in[12];
    float* out = (float*)d_out;

    char* ws = (char*)d_ws;
    size_t off = 0;
    auto alloc = [&](size_t bytes) -> char* {
        char* p = ws + off;
        off = (off + bytes + 255) & ~(size_t)255;
        return p;
    };
    unsigned short* h0  = (unsigned short*)alloc((size_t)N_NODES * HID * 2);
    unsigned short* h1  = (unsigned short*)alloc((size_t)N_NODES * HID * 2);
    unsigned short* agg = (unsigned short*)alloc((size_t)N_NODES * HID * 2);
    unsigned int* stage = (unsigned int*)alloc((size_t)N_EDGES * 4);          // 12.8 MB
    int* offs           = (int*)alloc((size_t)NSEG * NBUCKP * 4);             // 3.3 MB

    const int lin_blocks = (N_NODES / 16 + 3) / 4;

    fc_kernel<<<lin_blocks, 256, 0, stream>>>(x, fcW, fcb, h0);
    bin_kernel<<<NSEG, 256, 0, stream>>>(ei, stage, offs);
    agg_kernel<<<NBUCK, 256, 0, stream>>>(h0, stage, offs, agg);
    sage_kernel<<<lin_blocks, 256, 0, stream>>>(agg, h0, Wl1, bl1, Wr1, h1,
                                                nullptr, nullptr, nullptr, 0);
    agg_kernel<<<NBUCK, 256, 0, stream>>>(h1, stage, offs, agg);
    sage_kernel<<<lin_blocks, 256, 0, stream>>>(agg, h1, Wl2, bl2, Wr2, nullptr,
                                                hW, hb, out, 1);
}